// Round 3
// baseline (3246.016 us; speedup 1.0000x reference)
//
#include <hip/hip_runtime.h>
#include <hip/hip_bf16.h>

// LSTMReg on MI355X — round 3: FUSED 2-layer pipelined megakernel.
// 32 blocks x 256 thr; block owns 16 chains through BOTH layers.
// Pipeline iteration t: L0 computes step t, L1 computes step t-1 (independent
// within the iteration -> 8 independent MFMA chains + 2 gate phases of ILP).
// L0's LDS h-buffer IS L1's input-fragment source (same values, same frag
// offsets) -> h1 never goes to HBM; no workspace. bf16 hi/lo 3-pass MFMA
// (verified numerics, absmax 2e-7). One barrier per iteration.

typedef short bf16x8 __attribute__((ext_vector_type(8)));
typedef short bf16x4 __attribute__((ext_vector_type(4)));
typedef float f32x4  __attribute__((ext_vector_type(4)));

#define MFMA16(A, B, C) __builtin_amdgcn_mfma_f32_16x16x32_bf16(A, B, C, 0, 0, 0)

constexpr int T_LEN = 1024;
constexpr int H     = 64;
constexpr int B_TOT = 512;
constexpr int NB    = 16;          // chains per block = MFMA N
constexpr int NTHR  = 256;         // 4 waves
constexpr int NBLK  = B_TOT / NB;  // 32

__device__ __forceinline__ short f2bf(float f) {
  unsigned u = __builtin_bit_cast(unsigned, f);
  unsigned r = (u + 0x7fffu + ((u >> 16) & 1u)) >> 16;  // RNE
  return (short)r;
}
__device__ __forceinline__ float bf2f(short s) {
  unsigned u = ((unsigned)(unsigned short)s) << 16;
  return __builtin_bit_cast(float, u);
}
__device__ __forceinline__ float sigm(float x) { return 1.0f / (1.0f + __expf(-x)); }
__device__ __forceinline__ float tanhf_(float x) { return 1.0f - 2.0f / (1.0f + __expf(2.0f * x)); }

// 12 MFMAs per gate-group: 3-pass hi/lo over 4 k-tiles (k0,k1 = input side;
// k2,k3 = recurrent side). a[g] accumulates (bias pre-loaded).
__device__ __forceinline__ void mfma12(
    const bf16x8 (&wh)[4][4], const bf16x8 (&wl)[4][4],
    bf16x8 k0h, bf16x8 k0l, bf16x8 k1h, bf16x8 k1l,
    bf16x8 k2h, bf16x8 k2l, bf16x8 k3h, bf16x8 k3l,
    f32x4 (&a)[4]) {
#pragma unroll
  for (int g = 0; g < 4; ++g) {
    f32x4 acc = a[g];
    acc = MFMA16(wh[g][0], k0h, acc);
    acc = MFMA16(wl[g][0], k0h, acc);
    acc = MFMA16(wh[g][0], k0l, acc);
    acc = MFMA16(wh[g][1], k1h, acc);
    acc = MFMA16(wl[g][1], k1h, acc);
    acc = MFMA16(wh[g][1], k1l, acc);
    acc = MFMA16(wh[g][2], k2h, acc);
    acc = MFMA16(wl[g][2], k2h, acc);
    acc = MFMA16(wh[g][2], k2l, acc);
    acc = MFMA16(wh[g][3], k3h, acc);
    acc = MFMA16(wl[g][3], k3h, acc);
    acc = MFMA16(wh[g][3], k3l, acc);
    a[g] = acc;
  }
}

// Gate math (torch order i,f,g,o); returns h_new, updates c.
__device__ __forceinline__ f32x4 lstm_gate(const f32x4 (&a)[4], f32x4& c) {
  f32x4 h;
#pragma unroll
  for (int r = 0; r < 4; ++r) {
    float ig = sigm(a[0][r]);
    float fg = sigm(a[1][r]);
    float gg = tanhf_(a[2][r]);
    float og = sigm(a[3][r]);
    float cc = fg * c[r] + ig * gg;
    c[r] = cc;
    h[r] = og * tanhf_(cc);
  }
  return h;
}

__global__ __launch_bounds__(NTHR, 1) void lstm_fused(
    const float* __restrict__ xin,
    const float* __restrict__ w_ih0, const float* __restrict__ w_hh0,
    const float* __restrict__ b_ih0, const float* __restrict__ b_hh0,
    const float* __restrict__ w_ih1, const float* __restrict__ w_hh1,
    const float* __restrict__ b_ih1, const float* __restrict__ b_hh1,
    const float* __restrict__ fc_w, const float* __restrict__ fc_b,
    float* __restrict__ out) {
  const int tid = threadIdx.x;
  const int w   = tid >> 6;   // wave -> h-rows 16w..16w+15 (both layers)
  const int l   = tid & 63;
  const int b   = l & 15;     // chain (MFMA col)
  const int lq  = l >> 4;     // k-quarter / D-row-quarter
  const int chain0 = blockIdx.x * NB;

  // [buf][hi/lo][chain][feat(+pad to 72: 2-way max bank alias)]
  __shared__ __align__(16) short h0buf[2][2][NB][72];
  __shared__ __align__(16) short h1buf[2][2][NB][72];
  __shared__ float fcw_s[H];
  __shared__ float hfin[NB][H];

  for (int i = tid; i < 2 * 2 * NB * 72; i += NTHR) {
    ((short*)h0buf)[i] = 0;
    ((short*)h1buf)[i] = 0;
  }
  if (tid < H) fcw_s[tid] = fc_w[tid];

  // ---- one-time: W fragments (hi/lo) for BOTH layers into VGPRs ----
  const float* wih[2] = {w_ih0, w_ih1};
  const float* whh[2] = {w_hh0, w_hh1};
  const float* bih[2] = {b_ih0, b_ih1};
  const float* bhh[2] = {b_hh0, b_hh1};
  bf16x8 whi[2][4][4], wlo[2][4][4];  // [layer][gate][kt] -> 256 VGPR
  f32x4  biasf[2][4];
#pragma unroll
  for (int L = 0; L < 2; ++L) {
#pragma unroll
    for (int g = 0; g < 4; ++g) {
#pragma unroll
      for (int kt = 0; kt < 4; ++kt) {
        const int row = 64 * g + 16 * w + b;
        const int k0  = 32 * kt + 8 * lq;
        const float* src = (k0 < 64) ? &wih[L][row * 64 + k0]
                                     : &whh[L][row * 64 + (k0 - 64)];
        float4 v0 = *reinterpret_cast<const float4*>(src);
        float4 v1 = *reinterpret_cast<const float4*>(src + 4);
        float vv[8] = {v0.x, v0.y, v0.z, v0.w, v1.x, v1.y, v1.z, v1.w};
        bf16x8 hi8, lo8;
#pragma unroll
        for (int e = 0; e < 8; ++e) {
          short hh = f2bf(vv[e]);
          hi8[e] = hh;
          lo8[e] = f2bf(vv[e] - bf2f(hh));
        }
        whi[L][g][kt] = hi8;
        wlo[L][g][kt] = lo8;
      }
#pragma unroll
      for (int r = 0; r < 4; ++r) {
        int row = 64 * g + 16 * w + 4 * lq + r;
        biasf[L][g][r] = bih[L][row] + bhh[L][row];
      }
    }
  }

  // ---- x prefetch: xfrags = conv(x[0]); xf32 = raw x[1] ----
  const float* xptr = xin + (size_t)(chain0 + b) * T_LEN * H + 8 * lq;
  bf16x8 xk0h, xk0l, xk1h, xk1l;
  float4 xf32[4];
  {
    float4 r0 = *reinterpret_cast<const float4*>(xptr);
    float4 r1 = *reinterpret_cast<const float4*>(xptr + 4);
    float4 r2 = *reinterpret_cast<const float4*>(xptr + 32);
    float4 r3 = *reinterpret_cast<const float4*>(xptr + 36);
    float vv[16] = {r0.x, r0.y, r0.z, r0.w, r1.x, r1.y, r1.z, r1.w,
                    r2.x, r2.y, r2.z, r2.w, r3.x, r3.y, r3.z, r3.w};
#pragma unroll
    for (int e = 0; e < 8; ++e) {
      short hh = f2bf(vv[e]);
      xk0h[e] = hh;
      xk0l[e] = f2bf(vv[e] - bf2f(hh));
      short h2 = f2bf(vv[8 + e]);
      xk1h[e] = h2;
      xk1l[e] = f2bf(vv[8 + e] - bf2f(h2));
    }
    const float* p = xptr + H;  // x[1]
    xf32[0] = *reinterpret_cast<const float4*>(p);
    xf32[1] = *reinterpret_cast<const float4*>(p + 4);
    xf32[2] = *reinterpret_cast<const float4*>(p + 32);
    xf32[3] = *reinterpret_cast<const float4*>(p + 36);
  }

  __syncthreads();

  f32x4 creg0 = {0.f, 0.f, 0.f, 0.f};
  f32x4 creg1 = {0.f, 0.f, 0.f, 0.f};
  const int hoff = 16 * w + 4 * lq;

  for (int t = 0; t <= T_LEN; ++t) {
    const int cur = t & 1, nxt = cur ^ 1;

    // h0[t-1] frags: L0's recurrent side AND L1's input side (same values).
    const short* hb0 = &h0buf[cur][0][b][0];
    const short* lb0 = &h0buf[cur][1][b][0];
    bf16x8 g0h = *reinterpret_cast<const bf16x8*>(hb0 + 8 * lq);
    bf16x8 g1h = *reinterpret_cast<const bf16x8*>(hb0 + 32 + 8 * lq);
    bf16x8 g0l = *reinterpret_cast<const bf16x8*>(lb0 + 8 * lq);
    bf16x8 g1l = *reinterpret_cast<const bf16x8*>(lb0 + 32 + 8 * lq);
    // h2[t-2] frags: L1's recurrent side.
    const short* hb1 = &h1buf[cur][0][b][0];
    const short* lb1 = &h1buf[cur][1][b][0];
    bf16x8 m0h = *reinterpret_cast<const bf16x8*>(hb1 + 8 * lq);
    bf16x8 m1h = *reinterpret_cast<const bf16x8*>(hb1 + 32 + 8 * lq);
    bf16x8 m0l = *reinterpret_cast<const bf16x8*>(lb1 + 8 * lq);
    bf16x8 m1l = *reinterpret_cast<const bf16x8*>(lb1 + 32 + 8 * lq);

    // ---- L0 step t ----
    if (t < T_LEN) {
      f32x4 a[4] = {biasf[0][0], biasf[0][1], biasf[0][2], biasf[0][3]};
      mfma12(whi[0], wlo[0], xk0h, xk0l, xk1h, xk1l, g0h, g0l, g1h, g1l, a);
      f32x4 h0n = lstm_gate(a, creg0);
      bf16x4 h4, l4;
#pragma unroll
      for (int r = 0; r < 4; ++r) {
        short hh = f2bf(h0n[r]);
        h4[r] = hh;
        l4[r] = f2bf(h0n[r] - bf2f(hh));
      }
      *reinterpret_cast<bf16x4*>(&h0buf[nxt][0][b][hoff]) = h4;
      *reinterpret_cast<bf16x4*>(&h0buf[nxt][1][b][hoff]) = l4;
    }

    // ---- L1 step t-1 (independent of L0 step t) ----
    if (t >= 1) {
      f32x4 a[4] = {biasf[1][0], biasf[1][1], biasf[1][2], biasf[1][3]};
      mfma12(whi[1], wlo[1], g0h, g0l, g1h, g1l, m0h, m0l, m1h, m1l, a);
      f32x4 h1n = lstm_gate(a, creg1);
      bf16x4 h4, l4;
#pragma unroll
      for (int r = 0; r < 4; ++r) {
        short hh = f2bf(h1n[r]);
        h4[r] = hh;
        l4[r] = f2bf(h1n[r] - bf2f(hh));
      }
      *reinterpret_cast<bf16x4*>(&h1buf[nxt][0][b][hoff]) = h4;
      *reinterpret_cast<bf16x4*>(&h1buf[nxt][1][b][hoff]) = l4;
      if (t == T_LEN) {
#pragma unroll
        for (int r = 0; r < 4; ++r) hfin[b][hoff + r] = h1n[r];
      }
    }

    // ---- x pipeline: convert x[t+1] (raw regs), then load raw x[t+2] ----
    if (t < T_LEN - 1) {
      float vv[16] = {xf32[0].x, xf32[0].y, xf32[0].z, xf32[0].w,
                      xf32[1].x, xf32[1].y, xf32[1].z, xf32[1].w,
                      xf32[2].x, xf32[2].y, xf32[2].z, xf32[2].w,
                      xf32[3].x, xf32[3].y, xf32[3].z, xf32[3].w};
#pragma unroll
      for (int e = 0; e < 8; ++e) {
        short hh = f2bf(vv[e]);
        xk0h[e] = hh;
        xk0l[e] = f2bf(vv[e] - bf2f(hh));
        short h2 = f2bf(vv[8 + e]);
        xk1h[e] = h2;
        xk1l[e] = f2bf(vv[8 + e] - bf2f(h2));
      }
      if (t < T_LEN - 2) {
        const float* p = xptr + (size_t)(t + 2) * H;
        xf32[0] = *reinterpret_cast<const float4*>(p);
        xf32[1] = *reinterpret_cast<const float4*>(p + 4);
        xf32[2] = *reinterpret_cast<const float4*>(p + 32);
        xf32[3] = *reinterpret_cast<const float4*>(p + 36);
      }
    }

    __syncthreads();
  }

  // ---- FC epilogue: out = fc_w . h2[T-1] + fc_b ----
  if (tid < NB) {
    float acc = fc_b[0];
#pragma unroll
    for (int h = 0; h < H; ++h) acc += fcw_s[h] * hfin[tid][h];
    out[chain0 + tid] = acc;
  }
}

extern "C" void kernel_launch(void* const* d_in, const int* in_sizes, int n_in,
                              void* d_out, int out_size, void* d_ws, size_t ws_size,
                              hipStream_t stream) {
  const float* x     = (const float*)d_in[0];
  const float* w_ih0 = (const float*)d_in[1];
  const float* w_hh0 = (const float*)d_in[2];
  const float* b_ih0 = (const float*)d_in[3];
  const float* b_hh0 = (const float*)d_in[4];
  const float* w_ih1 = (const float*)d_in[5];
  const float* w_hh1 = (const float*)d_in[6];
  const float* b_ih1 = (const float*)d_in[7];
  const float* b_hh1 = (const float*)d_in[8];
  const float* fc_w  = (const float*)d_in[9];
  const float* fc_b  = (const float*)d_in[10];
  float* out = (float*)d_out;

  lstm_fused<<<dim3(NBLK), dim3(NTHR), 0, stream>>>(
      x, w_ih0, w_hh0, b_ih0, b_hh0, w_ih1, w_hh1, b_ih1, b_hh1,
      fc_w, fc_b, out);
}

// Round 4
// 2240.376 us; speedup vs baseline: 1.4489x; 1.4489x over previous
//
#include <hip/hip_runtime.h>
#include <hip/hip_bf16.h>

// LSTMReg on MI355X — round 4: fused 2-layer pipeline, LAYER-SPLIT WAVES.
// 32 blocks x 512 thr (8 waves). Waves 0-3: layer0 step t; waves 4-7:
// layer1 step t-1 (independent). Each wave holds only its layer's weight
// frags (128 VGPR) -> no spill (round-3 lesson). 2 waves/SIMD overlap.
// h0/h1 live in fragment-linear LDS (conflict-free reads at base+16*lane);
// h1 never touches HBM. x is pre-converted to bf16 hi/lo fragment order by
// a separate memory-bound kernel into d_ws (128 MiB exactly).
// bf16 hi/lo 3-pass MFMA (absmax 2e-7 verified in rounds 2-3).

typedef short bf16x8 __attribute__((ext_vector_type(8)));
typedef short bf16x4 __attribute__((ext_vector_type(4)));
typedef float f32x4  __attribute__((ext_vector_type(4)));

#define MFMA16(A, B, C) __builtin_amdgcn_mfma_f32_16x16x32_bf16(A, B, C, 0, 0, 0)

constexpr int T_LEN = 1024;
constexpr int H     = 64;
constexpr int NB    = 16;          // chains per block = MFMA N
constexpr int NTHR  = 512;         // 8 waves
constexpr int NBLK  = 32;          // 512 chains / 16

// x fragment buffer layout: [blk][t][lane(64)][frag(4)][8 shorts]
// frag order: kt0h, kt1h, kt0l, kt1l. 64 B per lane per t.
constexpr int    XT_SHORTS   = 64 * 32;                       // 2048
constexpr size_t XBLK_SHORTS = (size_t)T_LEN * XT_SHORTS;     // 4 MiB per block

__device__ __forceinline__ short f2bf(float f) {
  unsigned u = __builtin_bit_cast(unsigned, f);
  unsigned r = (u + 0x7fffu + ((u >> 16) & 1u)) >> 16;  // RNE
  return (short)r;
}
__device__ __forceinline__ float bf2f(short s) {
  unsigned u = ((unsigned)(unsigned short)s) << 16;
  return __builtin_bit_cast(float, u);
}
__device__ __forceinline__ float sigm(float x) { return 1.0f / (1.0f + __expf(-x)); }
__device__ __forceinline__ float tanhf_(float x) { return 1.0f - 2.0f / (1.0f + __expf(2.0f * x)); }

// ---- pre-pass: x [512][1024][64] fp32 -> fragment-order bf16 hi/lo ----
__global__ __launch_bounds__(256, 4) void xconv(const float* __restrict__ x,
                                                short* __restrict__ xf) {
  const int g  = blockIdx.x * 256 + threadIdx.x;  // (blk,b,t,lq), lq fastest
  const int lq = g & 3;
  const int t  = (g >> 2) & (T_LEN - 1);
  const int b  = (g >> 12) & 15;
  const int blk = g >> 16;
  const float* src = x + ((size_t)(blk * NB + b) * T_LEN + t) * H + 8 * lq;
  float4 v0 = *reinterpret_cast<const float4*>(src);
  float4 v1 = *reinterpret_cast<const float4*>(src + 4);
  float4 v2 = *reinterpret_cast<const float4*>(src + 32);
  float4 v3 = *reinterpret_cast<const float4*>(src + 36);
  float a[8] = {v0.x, v0.y, v0.z, v0.w, v1.x, v1.y, v1.z, v1.w};
  float c[8] = {v2.x, v2.y, v2.z, v2.w, v3.x, v3.y, v3.z, v3.w};
  bf16x8 k0h, k0l, k1h, k1l;
#pragma unroll
  for (int e = 0; e < 8; ++e) {
    short h0 = f2bf(a[e]);
    k0h[e] = h0;
    k0l[e] = f2bf(a[e] - bf2f(h0));
    short h1 = f2bf(c[e]);
    k1h[e] = h1;
    k1l[e] = f2bf(c[e] - bf2f(h1));
  }
  short* dst = xf + (size_t)blk * XBLK_SHORTS + (size_t)t * XT_SHORTS +
               (lq * 16 + b) * 32;
  *reinterpret_cast<bf16x8*>(dst + 0)  = k0h;
  *reinterpret_cast<bf16x8*>(dst + 8)  = k1h;
  *reinterpret_cast<bf16x8*>(dst + 16) = k0l;
  *reinterpret_cast<bf16x8*>(dst + 24) = k1l;
}

// 12 MFMAs per gate: 3-pass hi/lo over 4 k-tiles (in-side k0,k1; rec-side k2,k3)
__device__ __forceinline__ void mfma12(
    const bf16x8 (&wh)[4][4], const bf16x8 (&wl)[4][4],
    bf16x8 k0h, bf16x8 k0l, bf16x8 k1h, bf16x8 k1l,
    bf16x8 k2h, bf16x8 k2l, bf16x8 k3h, bf16x8 k3l,
    f32x4 (&a)[4]) {
#pragma unroll
  for (int g = 0; g < 4; ++g) {
    f32x4 acc = a[g];
    acc = MFMA16(wh[g][0], k0h, acc);
    acc = MFMA16(wl[g][0], k0h, acc);
    acc = MFMA16(wh[g][0], k0l, acc);
    acc = MFMA16(wh[g][1], k1h, acc);
    acc = MFMA16(wl[g][1], k1h, acc);
    acc = MFMA16(wh[g][1], k1l, acc);
    acc = MFMA16(wh[g][2], k2h, acc);
    acc = MFMA16(wl[g][2], k2h, acc);
    acc = MFMA16(wh[g][2], k2l, acc);
    acc = MFMA16(wh[g][3], k3h, acc);
    acc = MFMA16(wl[g][3], k3h, acc);
    acc = MFMA16(wh[g][3], k3l, acc);
    a[g] = acc;
  }
}

__device__ __forceinline__ f32x4 lstm_gate(const f32x4 (&a)[4], f32x4& c) {
  f32x4 h;
#pragma unroll
  for (int r = 0; r < 4; ++r) {
    float ig = sigm(a[0][r]);
    float fg = sigm(a[1][r]);
    float gg = tanhf_(a[2][r]);
    float og = sigm(a[3][r]);
    float cc = fg * c[r] + ig * gg;
    c[r] = cc;
    h[r] = og * tanhf_(cc);
  }
  return h;
}

__global__ __launch_bounds__(NTHR, 2) void lstm_fused(
    const short* __restrict__ xf,
    const float* __restrict__ w_ih0, const float* __restrict__ w_hh0,
    const float* __restrict__ b_ih0, const float* __restrict__ b_hh0,
    const float* __restrict__ w_ih1, const float* __restrict__ w_hh1,
    const float* __restrict__ b_ih1, const float* __restrict__ b_hh1,
    const float* __restrict__ fc_w, const float* __restrict__ fc_b,
    float* __restrict__ out) {
  const int tid   = threadIdx.x;
  const int wv    = tid >> 6;
  const int group = wv >> 2;   // 0 = layer0, 1 = layer1
  const int sw    = wv & 3;    // h-row slice 16*sw..16*sw+15
  const int l     = tid & 63;
  const int b     = l & 15;    // chain (MFMA col)
  const int lq    = l >> 4;    // k-quarter / D-row-quarter
  const int blk   = blockIdx.x;
  const int chain0 = blk * NB;

  // fragment-linear h buffers: [buf][part(hi/lo)][kts][lane][8 shorts]
  // reader lane l: 16B at +16*l  (2 lanes/bank = free)
  __shared__ __align__(16) short h0buf[2][2][2][64][8];  // 8 KiB
  __shared__ __align__(16) short h1buf[2][2][2][64][8];  // 8 KiB
  __shared__ float bias_s[2][256];
  __shared__ float fcw_s[H];
  __shared__ float hfin[NB][H];

  for (int i = tid; i < 2 * 2 * 2 * 64 * 8; i += NTHR) {
    ((short*)h0buf)[i] = 0;
    ((short*)h1buf)[i] = 0;
  }
  if (tid < 256)      bias_s[0][tid] = b_ih0[tid] + b_hh0[tid];
  else                bias_s[1][tid - 256] = b_ih1[tid - 256] + b_hh1[tid - 256];
  if (tid < H) fcw_s[tid] = fc_w[tid];

  // ---- this wave's layer weights -> VGPR frags (hi/lo) ----
  const float* wih = group ? w_ih1 : w_ih0;
  const float* whh = group ? w_hh1 : w_hh0;
  bf16x8 whi[4][4], wlo[4][4];  // [gate][kt] = 128 VGPR
#pragma unroll
  for (int g = 0; g < 4; ++g) {
#pragma unroll
    for (int kt = 0; kt < 4; ++kt) {
      const int row = 64 * g + 16 * sw + b;
      const int k0  = 32 * kt + 8 * lq;
      const float* src = (k0 < 64) ? &wih[row * 64 + k0] : &whh[row * 64 + (k0 - 64)];
      float4 v0 = *reinterpret_cast<const float4*>(src);
      float4 v1 = *reinterpret_cast<const float4*>(src + 4);
      float vv[8] = {v0.x, v0.y, v0.z, v0.w, v1.x, v1.y, v1.z, v1.w};
      bf16x8 hi8, lo8;
#pragma unroll
      for (int e = 0; e < 8; ++e) {
        short hh = f2bf(vv[e]);
        hi8[e] = hh;
        lo8[e] = f2bf(vv[e] - bf2f(hh));
      }
      whi[g][kt] = hi8;
      wlo[g][kt] = lo8;
    }
  }

  // ---- x pipeline (group 0 only): per-lane 64B frag packet per t ----
  const short* xfl = xf + (size_t)blk * XBLK_SHORTS + (size_t)l * 32;
  bf16x8 xk0h, xk1h, xk0l, xk1l, xn0h, xn1h, xn0l, xn1l;
  if (group == 0) {
    xk0h = *reinterpret_cast<const bf16x8*>(xfl + 0);
    xk1h = *reinterpret_cast<const bf16x8*>(xfl + 8);
    xk0l = *reinterpret_cast<const bf16x8*>(xfl + 16);
    xk1l = *reinterpret_cast<const bf16x8*>(xfl + 24);
  }

  __syncthreads();

  f32x4 creg = {0.f, 0.f, 0.f, 0.f};
  // write mapping (derived; see round-4 notes): feature f = 16sw+4lq+r
  const int w_kts = sw >> 1;
  const int w_li  = (2 * (sw & 1) + (lq >> 1)) * 16 + b;
  const int w_e0  = 4 * (lq & 1);
  const int hoff  = 16 * sw + 4 * lq;

  for (int t = 0; t <= T_LEN; ++t) {
    const int cur = t & 1, nxt = cur ^ 1;

    // prefetch next x packet (consumed after the barrier)
    if (group == 0 && t + 1 < T_LEN) {
      const short* p = xfl + (size_t)(t + 1) * XT_SHORTS;
      xn0h = *reinterpret_cast<const bf16x8*>(p + 0);
      xn1h = *reinterpret_cast<const bf16x8*>(p + 8);
      xn0l = *reinterpret_cast<const bf16x8*>(p + 16);
      xn1l = *reinterpret_cast<const bf16x8*>(p + 24);
    }

    // h0[t-1] frags (L0 recurrent side; L1 input side) — conflict-free
    const short* p0 = &h0buf[cur][0][0][l][0];
    bf16x8 r0h = *reinterpret_cast<const bf16x8*>(p0);
    bf16x8 r1h = *reinterpret_cast<const bf16x8*>(p0 + 512);
    bf16x8 r0l = *reinterpret_cast<const bf16x8*>(p0 + 1024);
    bf16x8 r1l = *reinterpret_cast<const bf16x8*>(p0 + 1536);
    // h1[t-2] frags (L1 recurrent side)
    bf16x8 s0h, s1h, s0l, s1l;
    if (group == 1) {
      const short* p1 = &h1buf[cur][0][0][l][0];
      s0h = *reinterpret_cast<const bf16x8*>(p1);
      s1h = *reinterpret_cast<const bf16x8*>(p1 + 512);
      s0l = *reinterpret_cast<const bf16x8*>(p1 + 1024);
      s1l = *reinterpret_cast<const bf16x8*>(p1 + 1536);
    }

    const bool active = (group == 0) ? (t < T_LEN) : (t > 0);
    if (active) {
      f32x4 a[4];
#pragma unroll
      for (int g = 0; g < 4; ++g)
        a[g] = *reinterpret_cast<const f32x4*>(&bias_s[group][64 * g + 16 * sw + 4 * lq]);

      if (group == 0)
        mfma12(whi, wlo, xk0h, xk0l, xk1h, xk1l, r0h, r0l, r1h, r1l, a);
      else
        mfma12(whi, wlo, r0h, r0l, r1h, r1l, s0h, s0l, s1h, s1l, a);

      f32x4 hnew = lstm_gate(a, creg);

      if (group == 1 && t == T_LEN) {
#pragma unroll
        for (int r = 0; r < 4; ++r) hfin[b][hoff + r] = hnew[r];
      } else {
        bf16x4 h4, l4;
#pragma unroll
        for (int r = 0; r < 4; ++r) {
          short hh = f2bf(hnew[r]);
          h4[r] = hh;
          l4[r] = f2bf(hnew[r] - bf2f(hh));
        }
        short* dst = (group ? &h1buf[nxt][0][0][0][0] : &h0buf[nxt][0][0][0][0]) +
                     w_kts * 512 + w_li * 8 + w_e0;
        *reinterpret_cast<bf16x4*>(dst)        = h4;   // hi part
        *reinterpret_cast<bf16x4*>(dst + 1024) = l4;   // lo part
      }
    }

    __syncthreads();

    if (group == 0) { xk0h = xn0h; xk1h = xn1h; xk0l = xn0l; xk1l = xn1l; }
  }

  // ---- FC epilogue: out = fc_w . h2[T-1] + fc_b ----
  if (tid < NB) {
    float acc = fc_b[0];
#pragma unroll
    for (int h = 0; h < H; ++h) acc += fcw_s[h] * hfin[tid][h];
    out[chain0 + tid] = acc;
  }
}

extern "C" void kernel_launch(void* const* d_in, const int* in_sizes, int n_in,
                              void* d_out, int out_size, void* d_ws, size_t ws_size,
                              hipStream_t stream) {
  const float* x     = (const float*)d_in[0];
  const float* w_ih0 = (const float*)d_in[1];
  const float* w_hh0 = (const float*)d_in[2];
  const float* b_ih0 = (const float*)d_in[3];
  const float* b_hh0 = (const float*)d_in[4];
  const float* w_ih1 = (const float*)d_in[5];
  const float* w_hh1 = (const float*)d_in[6];
  const float* b_ih1 = (const float*)d_in[7];
  const float* b_hh1 = (const float*)d_in[8];
  const float* fc_w  = (const float*)d_in[9];
  const float* fc_b  = (const float*)d_in[10];
  float* out = (float*)d_out;

  short* xfrag = (short*)d_ws;  // 128 MiB exactly (availability proven round 1)

  // pre-pass: 32*16*1024*4 threads = 8192 blocks
  xconv<<<dim3(8192), dim3(256), 0, stream>>>(x, xfrag);
  lstm_fused<<<dim3(NBLK), dim3(NTHR), 0, stream>>>(
      xfrag, w_ih0, w_hh0, b_ih0, b_hh0, w_ih1, w_hh1, b_ih1, b_hh1,
      fc_w, fc_b, out);
}